// Round 4
// baseline (1430.900 us; speedup 1.0000x reference)
//
#include <hip/hip_runtime.h>
#include <math.h>

#define DEVI __device__ __forceinline__
typedef unsigned short u16;
typedef unsigned int u32;
typedef __bf16 bf16x8 __attribute__((ext_vector_type(8)));
typedef float f32x4 __attribute__((ext_vector_type(4)));

static constexpr int CAP = 8192;   // per (router,rank,expert) list capacity

DEVI u16 f2b(float f) {            // f32 -> bf16 bits, RNE
  u32 x = __builtin_bit_cast(u32, f);
  u32 r = (x + 0x7fffu + ((x >> 16) & 1u)) >> 16;
  return (u16)r;
}
DEVI float b2f(u16 u) { return __builtin_bit_cast(float, (u32)u << 16); }

DEVI void async16(const u16* g, u16* l) {
  __builtin_amdgcn_global_load_lds((__attribute__((address_space(1))) void*)g,
                                   (__attribute__((address_space(3))) void*)l, 16, 0, 0);
}

// ---------------- f32 -> bf16 conversion ----------------
__global__ void cvt_k(const float* __restrict__ s0, u16* __restrict__ d0, long n0) {
  long nq = n0 / 4;
  long stride = (long)gridDim.x * blockDim.x;
  for (long q = (long)blockIdx.x * blockDim.x + threadIdx.x; q < nq; q += stride) {
    float4 v = ((const float4*)s0)[q];
    ushort4 o;
    o.x = f2b(v.x); o.y = f2b(v.y); o.z = f2b(v.z); o.w = f2b(v.w);
    ((ushort4*)d0)[q] = o;
  }
}

// ---------------- fused router: 8 tokens/block, 1024 blocks ----------------
// Per block: x_addr (f64) for its 8 tokens, z (f64), top3+softmax, list push,
// bias init of out, and bf16 emission of x. ~22.4 KB LDS -> 4 blocks/CU.
__global__ __launch_bounds__(256) void xrouter_k(
    const float* __restrict__ x, const float* __restrict__ Pw,
    const float* __restrict__ U1, const float* __restrict__ U2, const float* __restrict__ U3,
    const float* __restrict__ b2,
    int* __restrict__ cnt, int* __restrict__ ltok, float* __restrict__ lwgt,
    float* __restrict__ out, u16* __restrict__ xb) {
  __shared__ __align__(16) char sm[22400];
  float*  xs  = (float*)sm;                    // [8][68]  f32  (2176 B)
  float*  pws = (float*)(sm + 2176);           // [64][68] f32  (17408 B) - stage A
  float*  us  = (float*)(sm + 2176);           // [36][68] f32  (9792 B)  - stage B (alias)
  double* xa  = (double*)(sm + 11968);         // [8][66]  f64  (4224 B)  - stage B (alias)
  double* zz  = (double*)(sm + 19584);         // [8][40]  f64  (2560 B)
  int*    se  = (int*)(sm + 22144);            // [8][4]
  float*  swg = (float*)(sm + 22272);          // [8][4]

  const int tid = threadIdx.x;
  const int tok0 = blockIdx.x * 8;
  const int tok = tid >> 5, dg = tid & 31;     // token 0..7, dim pair {dg, dg+32}

  double a0 = 0, a1 = 0, a2 = 0, a3 = 0;

  for (int kc = 0; kc < 16; ++kc) {            // 16 chunks of 64 k
    if (tid < 128) {                           // stage x [8][64] + emit bf16
      int t = tid >> 4, c4 = tid & 15;
      size_t goff = (size_t)(tok0 + t) * 1024 + kc * 64 + c4 * 4;
      float4 v = *(const float4*)&x[goff];
      *(float4*)&xs[t * 68 + c4 * 4] = v;
      ushort4 o; o.x = f2b(v.x); o.y = f2b(v.y); o.z = f2b(v.z); o.w = f2b(v.w);
      *(ushort4*)&xb[goff] = o;
    }
#pragma unroll
    for (int j = 0; j < 4; ++j) {              // stage Pw [64][64]
      int f = tid + 256 * j;
      int r = f >> 4, c4 = f & 15;
      *(float4*)&pws[r * 68 + c4 * 4] = *(const float4*)&Pw[(size_t)r * 1024 + kc * 64 + c4 * 4];
    }
    __syncthreads();
    const float* xrow = &xs[tok * 68];
    const float* p0 = &pws[dg * 68];
    const float* p1 = &pws[(dg + 32) * 68];
#pragma unroll
    for (int k4 = 0; k4 < 16; ++k4) {
      float4 xv = *(const float4*)&xrow[k4 * 4];
      float4 q0 = *(const float4*)&p0[k4 * 4];
      float4 q1 = *(const float4*)&p1[k4 * 4];
      a0 += (double)xv.x * q0.x + (double)xv.y * q0.y;
      a1 += (double)xv.z * q0.z + (double)xv.w * q0.w;
      a2 += (double)xv.x * q1.x + (double)xv.y * q1.y;
      a3 += (double)xv.z * q1.z + (double)xv.w * q1.w;
    }
    __syncthreads();
  }

  // write x_addr to LDS (aliases pws; all pws reads done) + stage U rows
  xa[tok * 66 + dg] = a0 + a1;
  xa[tok * 66 + dg + 32] = a2 + a3;
  if (tid < 144) {                             // 36 rows x 16 float4 = 576
#pragma unroll
    for (int j = 0; j < 4; ++j) {
      int f = tid * 4 + j;
      int r = f >> 4, c4 = f & 15;
      const float* U = (r < 12) ? (U1 + r * 64) : (r < 24 ? U2 + (r - 12) * 64 : U3 + (r - 24) * 64);
      *(float4*)&us[r * 68 + c4 * 4] = *(const float4*)&U[c4 * 4];
    }
  }
  __syncthreads();

  // z[tok][re] in f64: 8 tok x 36 re
#pragma unroll
  for (int rep = 0; rep < 2; ++rep) {
    int idx = tid + 256 * rep;
    int tk = idx >> 6, re = idx & 63;
    if (re < 36) {
      double acc = 0;
      const double* xr = &xa[tk * 66];
      const float* ur = &us[re * 68];
      for (int k = 0; k < 64; ++k) acc += xr[k] * (double)ur[k];
      zz[tk * 40 + re] = acc;
    }
  }
  __syncthreads();

  if (tid < 24) {                              // top-3 + softmax per (token, router)
    const int tk = tid & 7, r = tid >> 3;
    const double* z = &zz[tk * 40 + r * 12];
    double v0 = -1e300, v1 = -1e300, v2 = -1e300;
    int i0 = 0, i1 = 0, i2 = 0;
    for (int e = 0; e < 12; ++e) {
      double v = z[e];
      if (v > v0)      { v2 = v1; i2 = i1; v1 = v0; i1 = i0; v0 = v; i0 = e; }
      else if (v > v1) { v2 = v1; i2 = i1; v1 = v; i1 = e; }
      else if (v > v2) { v2 = v; i2 = e; }
    }
    const double inv_tau = 1.0 / (1.0 + 1e-8);
    double e1 = exp((v1 - v0) * inv_tau), e2 = exp((v2 - v0) * inv_tau);
    double s = 1.0 / (1.0 + e1 + e2);
    double w0 = s, w1 = e1 * s, w2 = e2 * s;
    int n = tok0 + tk;
    if (r < 2) {
      int jj3[3] = { i0, i1, i2 };
      double ww[3] = { w0, w1, w2 };
      for (int j = 0; j < 3; ++j) {
        int slot = (r * 3 + j) * 12 + jj3[j];
        int pos = atomicAdd(&cnt[slot], 1);
        ltok[slot * CAP + pos] = n;
        lwgt[slot * CAP + pos] = (float)ww[j];
      }
    } else {
      se[tk * 4 + 0] = i0; se[tk * 4 + 1] = i1; se[tk * 4 + 2] = i2;
      swg[tk * 4 + 0] = (float)w0; swg[tk * 4 + 1] = (float)w1; swg[tk * 4 + 2] = (float)w2;
    }
  }
  __syncthreads();

  // bias init of d_out (f32): out[n] = sum_j w3_j * b2[e3_j]
#pragma unroll
  for (int j = 0; j < 8; ++j) {
    int f = tid + 256 * j;                     // 0..2047 float4 slots
    int tk = f >> 8, c4 = f & 255;
    const float w0 = swg[tk * 4 + 0], w1 = swg[tk * 4 + 1], w2 = swg[tk * 4 + 2];
    float4 a = *(const float4*)&b2[(size_t)se[tk * 4 + 0] * 1024 + c4 * 4];
    float4 b = *(const float4*)&b2[(size_t)se[tk * 4 + 1] * 1024 + c4 * 4];
    float4 d = *(const float4*)&b2[(size_t)se[tk * 4 + 2] * 1024 + c4 * 4];
    float4 o;
    o.x = w0 * a.x + w1 * b.x + w2 * d.x;
    o.y = w0 * a.y + w1 * b.y + w2 * d.y;
    o.z = w0 * a.z + w1 * b.z + w2 * d.z;
    o.w = w0 * a.w + w1 * b.w + w2 * d.w;
    *(float4*)&out[(size_t)(tok0 + tk) * 1024 + c4 * 4] = o;
  }
}

// ---------------- tile descriptor build ----------------
__global__ void build_k(const int* __restrict__ cnt, int2* __restrict__ desc,
                        int* __restrict__ ntl) {
  int t = threadIdx.x;
  if (t < 6) {
    int nt = 0;
    for (int e = 0; e < 12; ++e) {
      int c = cnt[t * 12 + e];
      for (int s = 0; s < c; s += 128) { desc[t * 80 + nt] = make_int2(e, s); ++nt; }
    }
    ntl[t] = nt;
  }
}

// ---------------- grouped GEMM (T1 + T2 + T3-minimal dbuf pipeline) ----------------
// CT = u16 (bf16 RMW, used for h) or float (f32 RMW, used for d_out)
template<int K, int NOUT, bool ADD, typename CT>
__global__ __launch_bounds__(256) void moe_gemm(
    const u16* __restrict__ A, const u16* __restrict__ W, CT* __restrict__ C,
    const int* __restrict__ cnt12, const int* __restrict__ ltok12,
    const float* __restrict__ lwgt12,
    const int2* __restrict__ desc, const int* __restrict__ ntl) {
  // T1: XCD-chunked swizzle (nwg % 8 == 0 for both grids used)
  unsigned lin = blockIdx.y * gridDim.x + blockIdx.x;
  unsigned q = (gridDim.x * gridDim.y) >> 3;
  unsigned swz = (lin & 7) * q + (lin >> 3);
  int tile = swz % gridDim.x;
  int ntile = swz / gridDim.x;
  if (tile >= *ntl) return;
  const int2 dd = desc[tile];
  const int e = dd.x, rowStart = dd.y;
  const int rows = min(128, cnt12[e] - rowStart);
  const int base = e * CAP + rowStart;

  __shared__ __align__(16) u16 As[2][8192];    // 2 x 128 x 64
  __shared__ __align__(16) u16 Bs[2][8192];    // exactly 64 KB total

  const int tid = threadIdx.x;
  const int lane = tid & 63, w = tid >> 6;

  // T2 staging: linear LDS dest, inverse-swizzled global source column
  const int srcOff = (((lane & 7) ^ (lane >> 3)) * 8);
  const u16* aSrc[4]; const u16* bSrc[4];
#pragma unroll
  for (int i = 0; i < 4; ++i) {
    int r = (w * 4 + i) * 8 + (lane >> 3);
    int tok = ltok12[base + min(r, rows - 1)];
    aSrc[i] = A + (size_t)tok * K + srcOff;
    bSrc[i] = W + ((size_t)e * NOUT + ntile * 128 + r) * K + srcOff;
  }

  f32x4 acc[4][4] = {};
  const int wr = w >> 1, wc = w & 1;
  const int sx = (lane & 7) << 3;              // T2 read-side XOR (u16 units)
  const int hi8 = (lane >> 4) * 8;
  constexpr int NT = K / 64;

  // prologue: stage tile 0 into buffer 0
#pragma unroll
  for (int i = 0; i < 4; ++i) {
    async16(aSrc[i], &As[0][(w * 4 + i) * 512]);
    async16(bSrc[i], &Bs[0][(w * 4 + i) * 512]);
  }

  int cur = 0;
  for (int kt = 0; kt < NT; ++kt) {
    if (kt + 1 < NT) {                         // issue next tile's loads first
#pragma unroll
      for (int i = 0; i < 4; ++i) {
        async16(aSrc[i] + (kt + 1) * 64, &As[cur ^ 1][(w * 4 + i) * 512]);
        async16(bSrc[i] + (kt + 1) * 64, &Bs[cur ^ 1][(w * 4 + i) * 512]);
      }
      asm volatile("s_waitcnt vmcnt(8)" ::: "memory");   // old 8 (cur tile) done
    } else {
      asm volatile("s_waitcnt vmcnt(0)" ::: "memory");
    }
    __builtin_amdgcn_s_barrier();              // cur tile complete for all waves
#pragma unroll
    for (int kk = 0; kk < 2; ++kk) {
      bf16x8 af[4], bfr[4];
#pragma unroll
      for (int mi = 0; mi < 4; ++mi) {
        int rowA = wr * 64 + mi * 16 + (lane & 15);
        af[mi] = *(const bf16x8*)&As[cur][rowA * 64 + ((kk * 32 + hi8) ^ sx)];
      }
#pragma unroll
      for (int ni = 0; ni < 4; ++ni) {
        int rowB = wc * 64 + ni * 16 + (lane & 15);
        bfr[ni] = *(const bf16x8*)&Bs[cur][rowB * 64 + ((kk * 32 + hi8) ^ sx)];
      }
#pragma unroll
      for (int mi = 0; mi < 4; ++mi)
#pragma unroll
        for (int ni = 0; ni < 4; ++ni)
          acc[mi][ni] = __builtin_amdgcn_mfma_f32_16x16x32_bf16(af[mi], bfr[ni], acc[mi][ni], 0, 0, 0);
    }
    __builtin_amdgcn_s_barrier();              // all waves done reading cur
    cur ^= 1;
  }

  // epilogue: scaled scatter (RMW; bf16 pair-packed u32, f32 scalar)
#pragma unroll
  for (int mi = 0; mi < 4; ++mi) {
    int lr0 = wr * 64 + mi * 16 + ((lane >> 4) << 2);
#pragma unroll
    for (int rr = 0; rr < 4; ++rr) {
      int lrow = lr0 + rr;
      bool rowok = lrow < rows;
      int idx = base + (rowok ? lrow : 0);
      int tok = ltok12[idx];
      float wv = lwgt12[idx];
      if constexpr (sizeof(CT) == 2) {
        u32* cp32 = (u32*)((u16*)C + (size_t)tok * NOUT + ntile * 128 + wc * 64 + (lane & 14));
#pragma unroll
        for (int ni = 0; ni < 4; ++ni) {
          float v = acc[mi][ni][rr] * wv;
          float vo = __shfl_xor(v, 1);
          if (rowok && !(lane & 1)) {
            float lo = v, hi = vo;
            if (ADD) {
              u32 curv = cp32[ni * 8];
              lo += b2f((u16)(curv & 0xffffu));
              hi += b2f((u16)(curv >> 16));
            }
            cp32[ni * 8] = (u32)f2b(lo) | ((u32)f2b(hi) << 16);
          }
        }
      } else {
        if (rowok) {
          float* cp = (float*)C + (size_t)tok * NOUT + ntile * 128 + wc * 64 + (lane & 15);
#pragma unroll
          for (int ni = 0; ni < 4; ++ni) {
            float val = acc[mi][ni][rr] * wv;
            float* p = cp + ni * 16;
            *p = ADD ? (*p + val) : val;
          }
        }
      }
    }
  }
}

// ---------------- exact GELU in-place on bf16 h ----------------
DEVI float gelu1(float v) { return 0.5f * v * (1.0f + erff(v * 0.70710678118654752f)); }
DEVI u32 gpair(u32 u) {
  float lo = __builtin_bit_cast(float, (u & 0xffffu) << 16);
  float hi = __builtin_bit_cast(float, u & 0xffff0000u);
  return (u32)f2b(gelu1(lo)) | ((u32)f2b(gelu1(hi)) << 16);
}
__global__ void gelu_k(u32* __restrict__ h, long n4) {
  long stride = (long)gridDim.x * blockDim.x;
  uint4* p = (uint4*)h;
  for (long i = (long)blockIdx.x * blockDim.x + threadIdx.x; i < n4; i += stride) {
    uint4 v = p[i];
    v.x = gpair(v.x); v.y = gpair(v.y); v.z = gpair(v.z); v.w = gpair(v.w);
    p[i] = v;
  }
}

extern "C" void kernel_launch(void* const* d_in, const int* in_sizes, int n_in,
                              void* d_out, int out_size, void* d_ws, size_t ws_size,
                              hipStream_t stream) {
  const float* x  = (const float*)d_in[0];
  const float* Pw = (const float*)d_in[1];
  const float* U1 = (const float*)d_in[2];
  const float* U2 = (const float*)d_in[3];
  const float* U3 = (const float*)d_in[4];
  const float* W1 = (const float*)d_in[5];
  const float* W2 = (const float*)d_in[6];
  const float* b2 = (const float*)d_in[7];
  float* out = (float*)d_out;

  char* ws = (char*)d_ws;
  size_t o = 0;
  u16* Wb = (u16*)(ws + o); o += (size_t)12 * 4096 * 1024 * 2;  // W1b, later W2b
  u16* xb = (u16*)(ws + o); o += (size_t)8192 * 1024 * 2;
  u16* h  = (u16*)(ws + o); o += (size_t)8192 * 4096 * 2;
  int* cnt = (int*)(ws + o); o += 512;
  int2* desc = (int2*)(ws + o); o += (size_t)6 * 80 * sizeof(int2);
  o = (o + 255) & ~(size_t)255;
  int* ntl = (int*)(ws + o); o += 256;
  int* ltok = (int*)(ws + o); o += (size_t)6 * 12 * CAP * 4;
  float* lwgt = (float*)(ws + o); o += (size_t)6 * 12 * CAP * 4;
  if (ws_size < o) return;

  hipMemsetAsync(cnt, 0, 512, stream);
  cvt_k<<<4096, 256, 0, stream>>>(W1, Wb, (long)12 * 4096 * 1024);
  xrouter_k<<<1024, 256, 0, stream>>>(x, Pw, U1, U2, U3, b2, cnt, ltok, lwgt, out, xb);
  build_k<<<1, 64, 0, stream>>>(cnt, desc, ntl);

  { // layer 1: h = sum over ranks of w * (x @ W1[e]^T)   (bf16 RMW in ws)
    dim3 g(80, 32);
    int s;
    s = 0; moe_gemm<1024, 4096, false, u16><<<g, 256, 0, stream>>>(xb, Wb, h, cnt + s * 12, ltok + (size_t)s * 12 * CAP, lwgt + (size_t)s * 12 * CAP, desc + s * 80, ntl + s);
    s = 1; moe_gemm<1024, 4096, true , u16><<<g, 256, 0, stream>>>(xb, Wb, h, cnt + s * 12, ltok + (size_t)s * 12 * CAP, lwgt + (size_t)s * 12 * CAP, desc + s * 80, ntl + s);
    s = 2; moe_gemm<1024, 4096, true , u16><<<g, 256, 0, stream>>>(xb, Wb, h, cnt + s * 12, ltok + (size_t)s * 12 * CAP, lwgt + (size_t)s * 12 * CAP, desc + s * 80, ntl + s);
  }

  cvt_k<<<4096, 256, 0, stream>>>(W2, Wb, (long)12 * 1024 * 4096);
  gelu_k<<<2048, 256, 0, stream>>>((u32*)h, (long)8192 * 4096 / 8);

  { // layer 2: out += sum over ranks of w * (gelu(h) @ W2[e]^T)   (bias already in out, f32)
    dim3 g(80, 8);
    int s;
    s = 3; moe_gemm<4096, 1024, true, float><<<g, 256, 0, stream>>>(h, Wb, out, cnt + s * 12, ltok + (size_t)s * 12 * CAP, lwgt + (size_t)s * 12 * CAP, desc + s * 80, ntl + s);
    s = 4; moe_gemm<4096, 1024, true, float><<<g, 256, 0, stream>>>(h, Wb, out, cnt + s * 12, ltok + (size_t)s * 12 * CAP, lwgt + (size_t)s * 12 * CAP, desc + s * 80, ntl + s);
    s = 5; moe_gemm<4096, 1024, true, float><<<g, 256, 0, stream>>>(h, Wb, out, cnt + s * 12, ltok + (size_t)s * 12 * CAP, lwgt + (size_t)s * 12 * CAP, desc + s * 80, ntl + s);
  }
}

// Round 5
// 1322.839 us; speedup vs baseline: 1.0817x; 1.0817x over previous
//
#include <hip/hip_runtime.h>
#include <math.h>

#define DEVI __device__ __forceinline__
typedef unsigned short u16;
typedef unsigned int u32;
typedef __bf16 bf16x8 __attribute__((ext_vector_type(8)));
typedef float f32x4 __attribute__((ext_vector_type(4)));

static constexpr int CAP = 8192;   // per (router,rank,expert) list capacity

DEVI u16 f2b(float f) {            // f32 -> bf16 bits, RNE
  u32 x = __builtin_bit_cast(u32, f);
  u32 r = (x + 0x7fffu + ((x >> 16) & 1u)) >> 16;
  return (u16)r;
}
DEVI float b2f(u16 u) { return __builtin_bit_cast(float, (u32)u << 16); }

DEVI void async16(const u16* g, u16* l) {
  __builtin_amdgcn_global_load_lds((__attribute__((address_space(1))) void*)g,
                                   (__attribute__((address_space(3))) void*)l, 16, 0, 0);
}

// ---------------- f32 -> bf16 conversion ----------------
__global__ void cvt_k(const float* __restrict__ s0, u16* __restrict__ d0, long n0) {
  long nq = n0 / 4;
  long stride = (long)gridDim.x * blockDim.x;
  for (long q = (long)blockIdx.x * blockDim.x + threadIdx.x; q < nq; q += stride) {
    float4 v = ((const float4*)s0)[q];
    ushort4 o;
    o.x = f2b(v.x); o.y = f2b(v.y); o.z = f2b(v.z); o.w = f2b(v.w);
    ((ushort4*)d0)[q] = o;
  }
}

// ---------------- fused router: 8 tokens/block, 1024 blocks ----------------
__global__ __launch_bounds__(256) void xrouter_k(
    const float* __restrict__ x, const float* __restrict__ Pw,
    const float* __restrict__ U1, const float* __restrict__ U2, const float* __restrict__ U3,
    const float* __restrict__ b2,
    int* __restrict__ cnt, int* __restrict__ ltok, float* __restrict__ lwgt,
    float* __restrict__ out, u16* __restrict__ xb) {
  __shared__ __align__(16) char sm[22400];
  float*  xs  = (float*)sm;                    // [8][68]  f32
  float*  pws = (float*)(sm + 2176);           // [64][68] f32   (stage A)
  float*  us  = (float*)(sm + 2176);           // [36][68] f32   (stage B, alias)
  double* xa  = (double*)(sm + 11968);         // [8][66]  f64   (stage B, alias)
  double* zz  = (double*)(sm + 19584);         // [8][40]  f64
  int*    se  = (int*)(sm + 22144);            // [8][4]
  float*  swg = (float*)(sm + 22272);          // [8][4]

  const int tid = threadIdx.x;
  const int tok0 = blockIdx.x * 8;
  const int tok = tid >> 5, dg = tid & 31;

  double a0 = 0, a1 = 0, a2 = 0, a3 = 0;

  for (int kc = 0; kc < 16; ++kc) {
    if (tid < 128) {
      int t = tid >> 4, c4 = tid & 15;
      size_t goff = (size_t)(tok0 + t) * 1024 + kc * 64 + c4 * 4;
      float4 v = *(const float4*)&x[goff];
      *(float4*)&xs[t * 68 + c4 * 4] = v;
      ushort4 o; o.x = f2b(v.x); o.y = f2b(v.y); o.z = f2b(v.z); o.w = f2b(v.w);
      *(ushort4*)&xb[goff] = o;
    }
#pragma unroll
    for (int j = 0; j < 4; ++j) {
      int f = tid + 256 * j;
      int r = f >> 4, c4 = f & 15;
      *(float4*)&pws[r * 68 + c4 * 4] = *(const float4*)&Pw[(size_t)r * 1024 + kc * 64 + c4 * 4];
    }
    __syncthreads();
    const float* xrow = &xs[tok * 68];
    const float* p0 = &pws[dg * 68];
    const float* p1 = &pws[(dg + 32) * 68];
#pragma unroll
    for (int k4 = 0; k4 < 16; ++k4) {
      float4 xv = *(const float4*)&xrow[k4 * 4];
      float4 q0 = *(const float4*)&p0[k4 * 4];
      float4 q1 = *(const float4*)&p1[k4 * 4];
      a0 += (double)xv.x * q0.x + (double)xv.y * q0.y;
      a1 += (double)xv.z * q0.z + (double)xv.w * q0.w;
      a2 += (double)xv.x * q1.x + (double)xv.y * q1.y;
      a3 += (double)xv.z * q1.z + (double)xv.w * q1.w;
    }
    __syncthreads();
  }

  xa[tok * 66 + dg] = a0 + a1;
  xa[tok * 66 + dg + 32] = a2 + a3;
  if (tid < 144) {
#pragma unroll
    for (int j = 0; j < 4; ++j) {
      int f = tid * 4 + j;
      int r = f >> 4, c4 = f & 15;
      const float* U = (r < 12) ? (U1 + r * 64) : (r < 24 ? U2 + (r - 12) * 64 : U3 + (r - 24) * 64);
      *(float4*)&us[r * 68 + c4 * 4] = *(const float4*)&U[c4 * 4];
    }
  }
  __syncthreads();

#pragma unroll
  for (int rep = 0; rep < 2; ++rep) {
    int idx = tid + 256 * rep;
    int tk = idx >> 6, re = idx & 63;
    if (re < 36) {
      double acc = 0;
      const double* xr = &xa[tk * 66];
      const float* ur = &us[re * 68];
      for (int k = 0; k < 64; ++k) acc += xr[k] * (double)ur[k];
      zz[tk * 40 + re] = acc;
    }
  }
  __syncthreads();

  if (tid < 24) {
    const int tk = tid & 7, r = tid >> 3;
    const double* z = &zz[tk * 40 + r * 12];
    double v0 = -1e300, v1 = -1e300, v2 = -1e300;
    int i0 = 0, i1 = 0, i2 = 0;
    for (int e = 0; e < 12; ++e) {
      double v = z[e];
      if (v > v0)      { v2 = v1; i2 = i1; v1 = v0; i1 = i0; v0 = v; i0 = e; }
      else if (v > v1) { v2 = v1; i2 = i1; v1 = v; i1 = e; }
      else if (v > v2) { v2 = v; i2 = e; }
    }
    const double inv_tau = 1.0 / (1.0 + 1e-8);
    double e1 = exp((v1 - v0) * inv_tau), e2 = exp((v2 - v0) * inv_tau);
    double s = 1.0 / (1.0 + e1 + e2);
    double w0 = s, w1 = e1 * s, w2 = e2 * s;
    int n = tok0 + tk;
    if (r < 2) {
      int jj3[3] = { i0, i1, i2 };
      double ww[3] = { w0, w1, w2 };
      for (int j = 0; j < 3; ++j) {
        int slot = (r * 3 + j) * 12 + jj3[j];
        int pos = atomicAdd(&cnt[slot], 1);
        ltok[slot * CAP + pos] = n;
        lwgt[slot * CAP + pos] = (float)ww[j];
      }
    } else {
      se[tk * 4 + 0] = i0; se[tk * 4 + 1] = i1; se[tk * 4 + 2] = i2;
      swg[tk * 4 + 0] = (float)w0; swg[tk * 4 + 1] = (float)w1; swg[tk * 4 + 2] = (float)w2;
    }
  }
  __syncthreads();

#pragma unroll
  for (int j = 0; j < 8; ++j) {
    int f = tid + 256 * j;
    int tk = f >> 8, c4 = f & 255;
    const float w0 = swg[tk * 4 + 0], w1 = swg[tk * 4 + 1], w2 = swg[tk * 4 + 2];
    float4 a = *(const float4*)&b2[(size_t)se[tk * 4 + 0] * 1024 + c4 * 4];
    float4 b = *(const float4*)&b2[(size_t)se[tk * 4 + 1] * 1024 + c4 * 4];
    float4 d = *(const float4*)&b2[(size_t)se[tk * 4 + 2] * 1024 + c4 * 4];
    float4 o;
    o.x = w0 * a.x + w1 * b.x + w2 * d.x;
    o.y = w0 * a.y + w1 * b.y + w2 * d.y;
    o.z = w0 * a.z + w1 * b.z + w2 * d.z;
    o.w = w0 * a.w + w1 * b.w + w2 * d.w;
    *(float4*)&out[(size_t)(tok0 + tk) * 1024 + c4 * 4] = o;
  }
}

// ---------------- tile descriptor build (256-row tiles) ----------------
__global__ void build_k(const int* __restrict__ cnt, int2* __restrict__ desc,
                        int* __restrict__ ntl) {
  int t = threadIdx.x;
  if (t < 6) {
    int nt = 0;
    for (int e = 0; e < 12; ++e) {
      int c = cnt[t * 12 + e];
      for (int s = 0; s < c; s += 256) { desc[t * 48 + nt] = make_int2(e, s); ++nt; }
    }
    ntl[t] = nt;
  }
}

// ---------------- grouped GEMM: 256x256 tile, BK=64, 8 waves, dbuf, T1+T2 ----------------
// CT = u16 (bf16 RMW, used for h) or float (f32 RMW, used for d_out)
template<int K, int NOUT, bool ADD, typename CT>
__global__ __launch_bounds__(512, 2) void moe_gemm(
    const u16* __restrict__ A, const u16* __restrict__ W, CT* __restrict__ C,
    const int* __restrict__ cnt12, const int* __restrict__ ltok12,
    const float* __restrict__ lwgt12,
    const int2* __restrict__ desc, const int* __restrict__ ntl) {
  // T1: XCD-chunked swizzle (nwg % 8 == 0 for both grids used)
  unsigned lin = blockIdx.y * gridDim.x + blockIdx.x;
  unsigned q = (gridDim.x * gridDim.y) >> 3;
  unsigned swz = (lin & 7) * q + (lin >> 3);
  int tile = swz % gridDim.x;
  int ntile = swz / gridDim.x;
  if (tile >= *ntl) return;
  const int2 dd = desc[tile];
  const int e = dd.x, rowStart = dd.y;
  const int rows = min(256, cnt12[e] - rowStart);
  const int base = e * CAP + rowStart;

  __shared__ __align__(16) u16 As[2][16384];   // 2 x 256 x 64
  __shared__ __align__(16) u16 Bs[2][16384];   // 128 KB total
  __shared__ int tokL[256];
  __shared__ float wgtL[256];

  const int tid = threadIdx.x;
  const int lane = tid & 63, w = tid >> 6;
  if (tid < 256) {
    int li = min(tid, rows - 1);
    tokL[tid] = ltok12[base + li];
    wgtL[tid] = lwgt12[base + li];
  }
  __syncthreads();

  // T2 staging: linear LDS dest, inverse-swizzled global source column.
  // slot s = i*512 + tid -> row = i*64 + (tid>>3), col16 = tid&7, swz col16^(row&7)
  const int srcOff = (((tid & 7) ^ ((tid >> 3) & 7)) * 8);
  const u16* aSrc[4]; const u16* bSrc[4];
#pragma unroll
  for (int i = 0; i < 4; ++i) {
    int r = i * 64 + (tid >> 3);
    aSrc[i] = A + (size_t)tokL[min(r, rows - 1)] * K + srcOff;
    bSrc[i] = W + ((size_t)e * NOUT + ntile * 256 + r) * K + srcOff;
  }

  f32x4 acc[8][4] = {};
  const int wr = w >> 2, wc = w & 3;            // 2 x 4 wave grid
  const int sx = (lane & 7) << 3;               // T2 read-side XOR (u16 units)
  const int hi8 = (lane >> 4) * 8;
  constexpr int NT = K / 64;

  // prologue: stage tile 0 into buffer 0 (__syncthreads drains vmcnt)
#pragma unroll
  for (int i = 0; i < 4; ++i) {
    int s = i * 512 + tid;
    async16(aSrc[i], &As[0][s * 8]);
    async16(bSrc[i], &Bs[0][s * 8]);
  }
  __syncthreads();

  int cur = 0;
  for (int kt = 0; kt < NT; ++kt) {
    if (kt + 1 < NT) {                          // issue next tile BEFORE compute
#pragma unroll
      for (int i = 0; i < 4; ++i) {
        int s = i * 512 + tid;
        async16(aSrc[i] + (kt + 1) * 64, &As[cur ^ 1][s * 8]);
        async16(bSrc[i] + (kt + 1) * 64, &Bs[cur ^ 1][s * 8]);
      }
    }
#pragma unroll
    for (int kk = 0; kk < 2; ++kk) {
      bf16x8 bfr[4];
#pragma unroll
      for (int ni = 0; ni < 4; ++ni) {
        int rB = wc * 64 + ni * 16 + (lane & 15);
        bfr[ni] = *(const bf16x8*)&Bs[cur][rB * 64 + ((kk * 32 + hi8) ^ sx)];
      }
#pragma unroll
      for (int mi = 0; mi < 8; ++mi) {
        int rA = wr * 128 + mi * 16 + (lane & 15);
        bf16x8 af = *(const bf16x8*)&As[cur][rA * 64 + ((kk * 32 + hi8) ^ sx)];
#pragma unroll
        for (int ni = 0; ni < 4; ++ni)
          acc[mi][ni] = __builtin_amdgcn_mfma_f32_16x16x32_bf16(af, bfr[ni], acc[mi][ni], 0, 0, 0);
      }
    }
    __syncthreads();                            // drains vmcnt(0)+lgkm AFTER compute
    cur ^= 1;
  }

  // epilogue: scaled scatter (RMW; bf16 pair-packed u32, f32 scalar)
#pragma unroll
  for (int mi = 0; mi < 8; ++mi) {
    int lr0 = wr * 128 + mi * 16 + ((lane >> 4) << 2);
#pragma unroll
    for (int rr = 0; rr < 4; ++rr) {
      int lrow = lr0 + rr;
      bool rowok = lrow < rows;
      int tok = tokL[lrow];
      float wv = wgtL[lrow];
      if constexpr (sizeof(CT) == 2) {
        u32* cp32 = (u32*)((u16*)C + (size_t)tok * NOUT + ntile * 256 + wc * 64 + (lane & 14));
#pragma unroll
        for (int ni = 0; ni < 4; ++ni) {
          float v = acc[mi][ni][rr] * wv;
          float vo = __shfl_xor(v, 1);
          if (rowok && !(lane & 1)) {
            float lo = v, hi = vo;
            if (ADD) {
              u32 curv = cp32[ni * 8];
              lo += b2f((u16)(curv & 0xffffu));
              hi += b2f((u16)(curv >> 16));
            }
            cp32[ni * 8] = (u32)f2b(lo) | ((u32)f2b(hi) << 16);
          }
        }
      } else {
        if (rowok) {
          float* cp = (float*)C + (size_t)tok * NOUT + ntile * 256 + wc * 64 + (lane & 15);
#pragma unroll
          for (int ni = 0; ni < 4; ++ni) {
            float val = acc[mi][ni][rr] * wv;
            float* p = cp + ni * 16;
            *p = ADD ? (*p + val) : val;
          }
        }
      }
    }
  }
}

// ---------------- exact GELU in-place on bf16 h ----------------
DEVI float gelu1(float v) { return 0.5f * v * (1.0f + erff(v * 0.70710678118654752f)); }
DEVI u32 gpair(u32 u) {
  float lo = __builtin_bit_cast(float, (u & 0xffffu) << 16);
  float hi = __builtin_bit_cast(float, u & 0xffff0000u);
  return (u32)f2b(gelu1(lo)) | ((u32)f2b(gelu1(hi)) << 16);
}
__global__ void gelu_k(u32* __restrict__ h, long n4) {
  long stride = (long)gridDim.x * blockDim.x;
  uint4* p = (uint4*)h;
  for (long i = (long)blockIdx.x * blockDim.x + threadIdx.x; i < n4; i += stride) {
    uint4 v = p[i];
    v.x = gpair(v.x); v.y = gpair(v.y); v.z = gpair(v.z); v.w = gpair(v.w);
    p[i] = v;
  }
}

extern "C" void kernel_launch(void* const* d_in, const int* in_sizes, int n_in,
                              void* d_out, int out_size, void* d_ws, size_t ws_size,
                              hipStream_t stream) {
  const float* x  = (const float*)d_in[0];
  const float* Pw = (const float*)d_in[1];
  const float* U1 = (const float*)d_in[2];
  const float* U2 = (const float*)d_in[3];
  const float* U3 = (const float*)d_in[4];
  const float* W1 = (const float*)d_in[5];
  const float* W2 = (const float*)d_in[6];
  const float* b2 = (const float*)d_in[7];
  float* out = (float*)d_out;

  char* ws = (char*)d_ws;
  size_t o = 0;
  u16* Wb = (u16*)(ws + o); o += (size_t)12 * 4096 * 1024 * 2;  // W1b, later W2b
  u16* xb = (u16*)(ws + o); o += (size_t)8192 * 1024 * 2;
  u16* h  = (u16*)(ws + o); o += (size_t)8192 * 4096 * 2;
  int* cnt = (int*)(ws + o); o += 512;
  int2* desc = (int2*)(ws + o); o += (size_t)6 * 48 * sizeof(int2);
  o = (o + 255) & ~(size_t)255;
  int* ntl = (int*)(ws + o); o += 256;
  int* ltok = (int*)(ws + o); o += (size_t)6 * 12 * CAP * 4;
  float* lwgt = (float*)(ws + o); o += (size_t)6 * 12 * CAP * 4;
  if (ws_size < o) return;

  hipMemsetAsync(cnt, 0, 512, stream);
  cvt_k<<<4096, 256, 0, stream>>>(W1, Wb, (long)12 * 4096 * 1024);
  xrouter_k<<<1024, 256, 0, stream>>>(x, Pw, U1, U2, U3, b2, cnt, ltok, lwgt, out, xb);
  build_k<<<1, 64, 0, stream>>>(cnt, desc, ntl);

  { // layer 1: h = sum over ranks of w * (x @ W1[e]^T)   (bf16 RMW in ws)
    dim3 g(48, 16);
    int s;
    s = 0; moe_gemm<1024, 4096, false, u16><<<g, 512, 0, stream>>>(xb, Wb, h, cnt + s * 12, ltok + (size_t)s * 12 * CAP, lwgt + (size_t)s * 12 * CAP, desc + s * 48, ntl + s);
    s = 1; moe_gemm<1024, 4096, true , u16><<<g, 512, 0, stream>>>(xb, Wb, h, cnt + s * 12, ltok + (size_t)s * 12 * CAP, lwgt + (size_t)s * 12 * CAP, desc + s * 48, ntl + s);
    s = 2; moe_gemm<1024, 4096, true , u16><<<g, 512, 0, stream>>>(xb, Wb, h, cnt + s * 12, ltok + (size_t)s * 12 * CAP, lwgt + (size_t)s * 12 * CAP, desc + s * 48, ntl + s);
  }

  cvt_k<<<4096, 256, 0, stream>>>(W2, Wb, (long)12 * 1024 * 4096);
  gelu_k<<<2048, 256, 0, stream>>>((u32*)h, (long)8192 * 4096 / 8);

  { // layer 2: out += sum over ranks of w * (gelu(h) @ W2[e]^T)   (bias already in out, f32)
    dim3 g(48, 4);
    int s;
    s = 3; moe_gemm<4096, 1024, true, float><<<g, 512, 0, stream>>>(h, Wb, out, cnt + s * 12, ltok + (size_t)s * 12 * CAP, lwgt + (size_t)s * 12 * CAP, desc + s * 48, ntl + s);
    s = 4; moe_gemm<4096, 1024, true, float><<<g, 512, 0, stream>>>(h, Wb, out, cnt + s * 12, ltok + (size_t)s * 12 * CAP, lwgt + (size_t)s * 12 * CAP, desc + s * 48, ntl + s);
    s = 5; moe_gemm<4096, 1024, true, float><<<g, 512, 0, stream>>>(h, Wb, out, cnt + s * 12, ltok + (size_t)s * 12 * CAP, lwgt + (size_t)s * 12 * CAP, desc + s * 48, ntl + s);
  }
}